// Round 2
// baseline (835.813 us; speedup 1.0000x reference)
//
#include <hip/hip_runtime.h>
#include <hip/hip_bf16.h>

#define NNODES 50000
#define NEDGES 600000
#define DIM    128
#define NLAYERS 3
#define NCLS   10
#define NGRAPH 256
#define BN_EPS 1e-5f

// ---------------- CSR build ----------------

__global__ void count_deg(const int* __restrict__ dst, int* __restrict__ deg, int E) {
    int e = blockIdx.x * blockDim.x + threadIdx.x;
    if (e < E) atomicAdd(&deg[dst[e]], 1);
}

__global__ __launch_bounds__(1024) void scan_deg(const int* __restrict__ deg,
                                                 int* __restrict__ off,
                                                 int* __restrict__ cursor, int n) {
    __shared__ int s[1024];
    int t = threadIdx.x;
    const int CH = (n + 1023) / 1024;  // 49 for n=50000
    int lo = t * CH;
    int hi = lo + CH; if (hi > n) hi = n;
    int sum = 0;
    for (int i = lo; i < hi; ++i) sum += deg[i];
    s[t] = sum;
    __syncthreads();
    for (int o = 1; o < 1024; o <<= 1) {
        int v = (t >= o) ? s[t - o] : 0;
        __syncthreads();
        s[t] += v;
        __syncthreads();
    }
    int run = (t == 0) ? 0 : s[t - 1];
    for (int i = lo; i < hi; ++i) {
        off[i] = run; cursor[i] = run;
        run += deg[i];
    }
}

__global__ void fill_csr(const int* __restrict__ src, const int* __restrict__ dst,
                         const float* __restrict__ emask,
                         int* __restrict__ cursor,
                         int* __restrict__ csr_src, float* __restrict__ csr_w, int E) {
    int e = blockIdx.x * blockDim.x + threadIdx.x;
    if (e < E) {
        int d = dst[e];
        int p = atomicAdd(&cursor[d], 1);
        csr_src[p] = src[e];
        csr_w[p]   = emask[e];
    }
}

// ---------------- BN folding prep ----------------
// h' = (h - mean)*rsqrt(var+eps)*gamma + beta, h = dot + b1
// => dot*A + (b1*A + beta - mean*A);  colA = A, colB = b1*A + beta - mean*A
__global__ void prep_bn(const float* __restrict__ gamma, const float* __restrict__ beta,
                        const float* __restrict__ mean, const float* __restrict__ var,
                        const float* __restrict__ b1,
                        float* __restrict__ colA, float* __restrict__ colB, int n) {
    int i = blockIdx.x * blockDim.x + threadIdx.x;
    if (i < n) {
        float A = gamma[i] * rsqrtf(var[i] + BN_EPS);
        colA[i] = A;
        colB[i] = beta[i] - mean[i] * A + b1[i] * A;
    }
}

// ---------------- gathers (wave per node, float2 per lane) ----------------

__global__ __launch_bounds__(256) void gather0(const float* __restrict__ x,
                                               const int* __restrict__ off, const int* __restrict__ deg,
                                               const int* __restrict__ csr_src, const float* __restrict__ csr_w,
                                               const int* __restrict__ snmask,
                                               float* __restrict__ X, int n) {
    int wid  = (blockIdx.x * blockDim.x + threadIdx.x) >> 6;
    int lane = threadIdx.x & 63;
    if (wid >= n) return;
    int base = off[wid], dg = deg[wid];
    float2 acc = make_float2(0.f, 0.f);
    for (int j = 0; j < dg; ++j) {
        int s   = csr_src[base + j];
        float w = csr_w[base + j];
        float2 v = *(const float2*)&x[(long)s * DIM + lane * 2];
        acc.x = fmaf(w, v.x, acc.x);
        acc.y = fmaf(w, v.y, acc.y);
    }
    float2 res;
    if (snmask[wid]) {
        res = acc;
    } else {
        res = *(const float2*)&x[(long)wid * DIM + lane * 2];
    }
    *(float2*)&X[(long)wid * DIM + lane * 2] = res;
}

__global__ __launch_bounds__(256) void gatherL(const float* __restrict__ X,
                                               const int* __restrict__ off, const int* __restrict__ deg,
                                               const int* __restrict__ csr_src,
                                               float* __restrict__ H, int n) {
    int wid  = (blockIdx.x * blockDim.x + threadIdx.x) >> 6;
    int lane = threadIdx.x & 63;
    if (wid >= n) return;
    int base = off[wid], dg = deg[wid];
    float2 acc = *(const float2*)&X[(long)wid * DIM + lane * 2];  // self (GIN eps=0)
    for (int j = 0; j < dg; ++j) {
        int s = csr_src[base + j];
        float2 v = *(const float2*)&X[(long)s * DIM + lane * 2];
        acc.x += v.x; acc.y += v.y;
    }
    *(float2*)&H[(long)wid * DIM + lane * 2] = acc;
}

// ---------------- fused MLP: H -> Lin1 -> BN -> ReLU -> Lin2 -> ReLU -> X ----------------
// block: 256 threads, 32 rows. thread (tr=t>>4, tc=t&15) computes rows {tr,tr+16}, cols tc*8..tc*8+7

__global__ __launch_bounds__(256) void mlp_fused(const float* __restrict__ H, float* __restrict__ X,
                                                 const float* __restrict__ W1, const float* __restrict__ W2,
                                                 const float* __restrict__ colA, const float* __restrict__ colB,
                                                 const float* __restrict__ b2, int n) {
    __shared__ float in_t[32][132];
    __shared__ float h_t[32][132];
    int t = threadIdx.x;
    int row0 = blockIdx.x * 32;

    for (int i = 0; i < 4; ++i) {
        int idx = t + i * 256;
        int r = idx >> 5;
        int c = (idx & 31) * 4;
        int gr = row0 + r;
        float4 v = make_float4(0.f, 0.f, 0.f, 0.f);
        if (gr < n) v = *(const float4*)&H[(long)gr * DIM + c];
        *(float4*)&in_t[r][c] = v;
    }
    __syncthreads();

    int tr = t >> 4, tc = t & 15;
    int cb = tc * 8;

    float acc0[8], acc1[8];
#pragma unroll
    for (int j = 0; j < 8; ++j) { acc0[j] = 0.f; acc1[j] = 0.f; }

#pragma unroll 4
    for (int k = 0; k < DIM; ++k) {
        float a0 = in_t[tr][k];
        float a1 = in_t[tr + 16][k];
        float4 w0 = *(const float4*)&W1[k * DIM + cb];
        float4 w1 = *(const float4*)&W1[k * DIM + cb + 4];
        acc0[0] = fmaf(a0, w0.x, acc0[0]); acc0[1] = fmaf(a0, w0.y, acc0[1]);
        acc0[2] = fmaf(a0, w0.z, acc0[2]); acc0[3] = fmaf(a0, w0.w, acc0[3]);
        acc0[4] = fmaf(a0, w1.x, acc0[4]); acc0[5] = fmaf(a0, w1.y, acc0[5]);
        acc0[6] = fmaf(a0, w1.z, acc0[6]); acc0[7] = fmaf(a0, w1.w, acc0[7]);
        acc1[0] = fmaf(a1, w0.x, acc1[0]); acc1[1] = fmaf(a1, w0.y, acc1[1]);
        acc1[2] = fmaf(a1, w0.z, acc1[2]); acc1[3] = fmaf(a1, w0.w, acc1[3]);
        acc1[4] = fmaf(a1, w1.x, acc1[4]); acc1[5] = fmaf(a1, w1.y, acc1[5]);
        acc1[6] = fmaf(a1, w1.z, acc1[6]); acc1[7] = fmaf(a1, w1.w, acc1[7]);
    }

    // BN(affine-folded) + ReLU -> h_t
    {
        float4 A0 = *(const float4*)&colA[cb];
        float4 A1 = *(const float4*)&colA[cb + 4];
        float4 B0 = *(const float4*)&colB[cb];
        float4 B1 = *(const float4*)&colB[cb + 4];
        float4 r0, r1;
        r0.x = fmaxf(fmaf(acc0[0], A0.x, B0.x), 0.f);
        r0.y = fmaxf(fmaf(acc0[1], A0.y, B0.y), 0.f);
        r0.z = fmaxf(fmaf(acc0[2], A0.z, B0.z), 0.f);
        r0.w = fmaxf(fmaf(acc0[3], A0.w, B0.w), 0.f);
        r1.x = fmaxf(fmaf(acc0[4], A1.x, B1.x), 0.f);
        r1.y = fmaxf(fmaf(acc0[5], A1.y, B1.y), 0.f);
        r1.z = fmaxf(fmaf(acc0[6], A1.z, B1.z), 0.f);
        r1.w = fmaxf(fmaf(acc0[7], A1.w, B1.w), 0.f);
        *(float4*)&h_t[tr][cb]     = r0;
        *(float4*)&h_t[tr][cb + 4] = r1;
        r0.x = fmaxf(fmaf(acc1[0], A0.x, B0.x), 0.f);
        r0.y = fmaxf(fmaf(acc1[1], A0.y, B0.y), 0.f);
        r0.z = fmaxf(fmaf(acc1[2], A0.z, B0.z), 0.f);
        r0.w = fmaxf(fmaf(acc1[3], A0.w, B0.w), 0.f);
        r1.x = fmaxf(fmaf(acc1[4], A1.x, B1.x), 0.f);
        r1.y = fmaxf(fmaf(acc1[5], A1.y, B1.y), 0.f);
        r1.z = fmaxf(fmaf(acc1[6], A1.z, B1.z), 0.f);
        r1.w = fmaxf(fmaf(acc1[7], A1.w, B1.w), 0.f);
        *(float4*)&h_t[tr + 16][cb]     = r0;
        *(float4*)&h_t[tr + 16][cb + 4] = r1;
    }
    __syncthreads();

#pragma unroll
    for (int j = 0; j < 8; ++j) { acc0[j] = 0.f; acc1[j] = 0.f; }

#pragma unroll 4
    for (int k = 0; k < DIM; ++k) {
        float a0 = h_t[tr][k];
        float a1 = h_t[tr + 16][k];
        float4 w0 = *(const float4*)&W2[k * DIM + cb];
        float4 w1 = *(const float4*)&W2[k * DIM + cb + 4];
        acc0[0] = fmaf(a0, w0.x, acc0[0]); acc0[1] = fmaf(a0, w0.y, acc0[1]);
        acc0[2] = fmaf(a0, w0.z, acc0[2]); acc0[3] = fmaf(a0, w0.w, acc0[3]);
        acc0[4] = fmaf(a0, w1.x, acc0[4]); acc0[5] = fmaf(a0, w1.y, acc0[5]);
        acc0[6] = fmaf(a0, w1.z, acc0[6]); acc0[7] = fmaf(a0, w1.w, acc0[7]);
        acc1[0] = fmaf(a1, w0.x, acc1[0]); acc1[1] = fmaf(a1, w0.y, acc1[1]);
        acc1[2] = fmaf(a1, w0.z, acc1[2]); acc1[3] = fmaf(a1, w0.w, acc1[3]);
        acc1[4] = fmaf(a1, w1.x, acc1[4]); acc1[5] = fmaf(a1, w1.y, acc1[5]);
        acc1[6] = fmaf(a1, w1.z, acc1[6]); acc1[7] = fmaf(a1, w1.w, acc1[7]);
    }

    {
        float4 bb0 = *(const float4*)&b2[cb];
        float4 bb1 = *(const float4*)&b2[cb + 4];
        int gr0 = row0 + tr;
        int gr1 = row0 + tr + 16;
        if (gr0 < n) {
            float4 r0, r1;
            r0.x = fmaxf(acc0[0] + bb0.x, 0.f); r0.y = fmaxf(acc0[1] + bb0.y, 0.f);
            r0.z = fmaxf(acc0[2] + bb0.z, 0.f); r0.w = fmaxf(acc0[3] + bb0.w, 0.f);
            r1.x = fmaxf(acc0[4] + bb1.x, 0.f); r1.y = fmaxf(acc0[5] + bb1.y, 0.f);
            r1.z = fmaxf(acc0[6] + bb1.z, 0.f); r1.w = fmaxf(acc0[7] + bb1.w, 0.f);
            *(float4*)&X[(long)gr0 * DIM + cb]     = r0;
            *(float4*)&X[(long)gr0 * DIM + cb + 4] = r1;
        }
        if (gr1 < n) {
            float4 r0, r1;
            r0.x = fmaxf(acc1[0] + bb0.x, 0.f); r0.y = fmaxf(acc1[1] + bb0.y, 0.f);
            r0.z = fmaxf(acc1[2] + bb0.z, 0.f); r0.w = fmaxf(acc1[3] + bb0.w, 0.f);
            r1.x = fmaxf(acc1[4] + bb1.x, 0.f); r1.y = fmaxf(acc1[5] + bb1.y, 0.f);
            r1.z = fmaxf(acc1[6] + bb1.z, 0.f); r1.w = fmaxf(acc1[7] + bb1.w, 0.f);
            *(float4*)&X[(long)gr1 * DIM + cb]     = r0;
            *(float4*)&X[(long)gr1 * DIM + cb + 4] = r1;
        }
    }
}

// ---------------- pool (batch is sorted -> run-accumulate, few atomics) ----------------

__global__ __launch_bounds__(128) void pool_kernel(const float* __restrict__ X,
                                                   const int* __restrict__ batch,
                                                   float* __restrict__ POOL, int n) {
    int c  = threadIdx.x;          // channel
    int n0 = blockIdx.x * 128;
    if (n0 >= n) return;
    int n1 = n0 + 128; if (n1 > n) n1 = n;
    int gcur = batch[n0];
    float acc = 0.f;
    for (int i = n0; i < n1; ++i) {
        int g = batch[i];
        if (g != gcur) {
            atomicAdd(&POOL[(long)gcur * DIM + c], acc);
            acc = 0.f; gcur = g;
        }
        acc += X[(long)i * DIM + c];
    }
    atomicAdd(&POOL[(long)gcur * DIM + c], acc);
}

// ---------------- final head: relu(POOL@Wf1+bf1)@Wf2+bf2 ----------------

__global__ __launch_bounds__(128) void final_mlp(const float* __restrict__ POOL,
                                                 const float* __restrict__ Wf1, const float* __restrict__ bf1,
                                                 const float* __restrict__ Wf2, const float* __restrict__ bf2,
                                                 float* __restrict__ out) {
    int g = blockIdx.x;
    int t = threadIdx.x;  // 128
    __shared__ float p[128];
    __shared__ float h[128];
    p[t] = POOL[(long)g * DIM + t];
    __syncthreads();
    float acc = bf1[t];
#pragma unroll 8
    for (int k = 0; k < DIM; ++k) acc = fmaf(p[k], Wf1[k * DIM + t], acc);
    h[t] = fmaxf(acc, 0.f);
    __syncthreads();
    if (t < NCLS) {
        float acc2 = bf2[t];
#pragma unroll 8
        for (int k = 0; k < DIM; ++k) acc2 = fmaf(h[k], Wf2[k * NCLS + t], acc2);
        out[(long)g * NCLS + t] = acc2;
    }
}

// ---------------- launch ----------------

extern "C" void kernel_launch(void* const* d_in, const int* in_sizes, int n_in,
                              void* d_out, int out_size, void* d_ws, size_t ws_size,
                              hipStream_t stream) {
    const float* x      = (const float*)d_in[0];
    const int*   ei     = (const int*)d_in[1];
    const int*   snmask = (const int*)d_in[2];
    const float* emask  = (const float*)d_in[3];
    const int*   batch  = (const int*)d_in[4];
    const float* Ws1    = (const float*)d_in[5];
    const float* bs1    = (const float*)d_in[6];
    const float* gamma  = (const float*)d_in[7];
    const float* beta   = (const float*)d_in[8];
    const float* mean   = (const float*)d_in[9];
    const float* var    = (const float*)d_in[10];
    const float* Ws2    = (const float*)d_in[11];
    const float* bs2    = (const float*)d_in[12];
    const float* Wf1    = (const float*)d_in[13];
    const float* bf1    = (const float*)d_in[14];
    const float* Wf2    = (const float*)d_in[15];
    const float* bf2    = (const float*)d_in[16];
    float* out = (float*)d_out;

    const int* srcp = ei;
    const int* dstp = ei + NEDGES;

    char* ws = (char*)d_ws;
    size_t o = 0;
    auto alloc = [&](size_t bytes) -> void* {
        void* p = ws + o;
        o = (o + bytes + 255) & ~(size_t)255;
        return p;
    };
    float* X       = (float*)alloc((size_t)NNODES * DIM * 4);
    float* H       = (float*)alloc((size_t)NNODES * DIM * 4);
    int*   deg     = (int*)alloc((size_t)NNODES * 4);
    int*   off     = (int*)alloc((size_t)NNODES * 4);
    int*   cursor  = (int*)alloc((size_t)NNODES * 4);
    int*   csr_src = (int*)alloc((size_t)NEDGES * 4);
    float* csr_w   = (float*)alloc((size_t)NEDGES * 4);
    float* colA    = (float*)alloc((size_t)NLAYERS * DIM * 4);
    float* colB    = (float*)alloc((size_t)NLAYERS * DIM * 4);
    float* POOL    = (float*)alloc((size_t)NGRAPH * DIM * 4);

    (void)hipMemsetAsync(deg, 0, (size_t)NNODES * 4, stream);
    (void)hipMemsetAsync(POOL, 0, (size_t)NGRAPH * DIM * 4, stream);

    count_deg<<<(NEDGES + 255) / 256, 256, 0, stream>>>(dstp, deg, NEDGES);
    scan_deg<<<1, 1024, 0, stream>>>(deg, off, cursor, NNODES);
    fill_csr<<<(NEDGES + 255) / 256, 256, 0, stream>>>(srcp, dstp, emask, cursor, csr_src, csr_w, NEDGES);
    prep_bn<<<(NLAYERS * DIM + 255) / 256, 256, 0, stream>>>(gamma, beta, mean, var, bs1, colA, colB, NLAYERS * DIM);

    const int gatherBlocks = (NNODES * 64 + 255) / 256;  // wave per node
    gather0<<<gatherBlocks, 256, 0, stream>>>(x, off, deg, csr_src, csr_w, snmask, X, NNODES);

    const int mlpBlocks = (NNODES + 31) / 32;
    for (int l = 0; l < NLAYERS; ++l) {
        gatherL<<<gatherBlocks, 256, 0, stream>>>(X, off, deg, csr_src, H, NNODES);
        mlp_fused<<<mlpBlocks, 256, 0, stream>>>(H, X,
                                                 Ws1 + (size_t)l * DIM * DIM,
                                                 Ws2 + (size_t)l * DIM * DIM,
                                                 colA + (size_t)l * DIM,
                                                 colB + (size_t)l * DIM,
                                                 bs2 + (size_t)l * DIM, NNODES);
    }

    pool_kernel<<<(NNODES + 127) / 128, 128, 0, stream>>>(X, batch, POOL, NNODES);
    final_mlp<<<NGRAPH, 128, 0, stream>>>(POOL, Wf1, bf1, Wf2, bf2, out);
}

// Round 4
// 451.748 us; speedup vs baseline: 1.8502x; 1.8502x over previous
//
#include <hip/hip_runtime.h>
#include <hip/hip_bf16.h>

#define NNODES 50000
#define NEDGES 600000
#define DIM    128
#define NLAYERS 3
#define NCLS   10
#define NGRAPH 256
#define BN_EPS 1e-5f

typedef __attribute__((ext_vector_type(8))) short bf16x8;   // 8 bf16 = 4 VGPR
typedef __attribute__((ext_vector_type(4))) float f32x4;

static __device__ __forceinline__ unsigned short f2b(float f) {
    union { __hip_bfloat16 h; unsigned short u; } c;
    c.h = __float2bfloat16(f);
    return c.u;
}
static __device__ __forceinline__ float bflo(unsigned u) { return __uint_as_float(u << 16); }
static __device__ __forceinline__ float bfhi(unsigned u) { return __uint_as_float(u & 0xffff0000u); }
static __device__ __forceinline__ unsigned pack2(float a, float b) {
    return (unsigned)f2b(a) | ((unsigned)f2b(b) << 16);
}

// ---------------- CSR build ----------------

__global__ void count_deg(const int* __restrict__ dst, int* __restrict__ deg, int E) {
    int e = blockIdx.x * blockDim.x + threadIdx.x;
    if (e < E) atomicAdd(&deg[dst[e]], 1);
}

__global__ __launch_bounds__(1024) void scan_deg(const int* __restrict__ deg,
                                                 int* __restrict__ off,
                                                 int* __restrict__ cursor, int n) {
    __shared__ int s[1024];
    int t = threadIdx.x;
    const int CH = (n + 1023) / 1024;
    int lo = t * CH;
    int hi = lo + CH; if (hi > n) hi = n;
    int sum = 0;
    for (int i = lo; i < hi; ++i) sum += deg[i];
    s[t] = sum;
    __syncthreads();
    for (int o = 1; o < 1024; o <<= 1) {
        int v = (t >= o) ? s[t - o] : 0;
        __syncthreads();
        s[t] += v;
        __syncthreads();
    }
    int run = (t == 0) ? 0 : s[t - 1];
    for (int i = lo; i < hi; ++i) {
        off[i] = run; cursor[i] = run;
        run += deg[i];
    }
}

__global__ void fill_csr(const int* __restrict__ src, const int* __restrict__ dst,
                         const float* __restrict__ emask,
                         int* __restrict__ cursor,
                         int* __restrict__ csr_src, float* __restrict__ csr_w, int E) {
    int e = blockIdx.x * blockDim.x + threadIdx.x;
    if (e < E) {
        int d = dst[e];
        int p = atomicAdd(&cursor[d], 1);
        csr_src[p] = src[e];
        csr_w[p]   = emask[e];
    }
}

// ---------------- prep: BN fold, W transpose->bf16, x->bf16 ----------------

__global__ void prep_bn(const float* __restrict__ gamma, const float* __restrict__ beta,
                        const float* __restrict__ mean, const float* __restrict__ var,
                        const float* __restrict__ b1,
                        float* __restrict__ colA, float* __restrict__ colB, int n) {
    int i = blockIdx.x * blockDim.x + threadIdx.x;
    if (i < n) {
        float A = gamma[i] * rsqrtf(var[i] + BN_EPS);
        colA[i] = A;
        colB[i] = beta[i] - mean[i] * A + b1[i] * A;
    }
}

// W[l][k][n] f32  ->  WT[l][n][k] bf16
__global__ void prep_wt(const float* __restrict__ W1, const float* __restrict__ W2,
                        unsigned short* __restrict__ W1T, unsigned short* __restrict__ W2T, int total) {
    int i = blockIdx.x * blockDim.x + threadIdx.x;
    if (i < total) {
        int l  = i / (DIM * DIM);
        int r  = i - l * DIM * DIM;
        int nn = r / DIM;
        int kk = r - nn * DIM;
        int sidx = l * DIM * DIM + kk * DIM + nn;
        W1T[i] = f2b(W1[sidx]);
        W2T[i] = f2b(W2[sidx]);
    }
}

__global__ void conv_x(const float* __restrict__ x, unsigned short* __restrict__ xb, int n4) {
    int i = blockIdx.x * blockDim.x + threadIdx.x;
    if (i < n4) {
        float4 v = ((const float4*)x)[i];
        unsigned lo = pack2(v.x, v.y);
        unsigned hi = pack2(v.z, v.w);
        ((uint2*)xb)[i] = make_uint2(lo, hi);
    }
}

// ---------------- gathers (wave per node, u32=2bf16 per lane) ----------------

__global__ __launch_bounds__(256) void gather0(const unsigned short* __restrict__ xb,
                                               const int* __restrict__ off, const int* __restrict__ deg,
                                               const int* __restrict__ csr_src, const float* __restrict__ csr_w,
                                               const int* __restrict__ snmask,
                                               unsigned short* __restrict__ X, int n) {
    int wid  = (blockIdx.x * blockDim.x + threadIdx.x) >> 6;
    int lane = threadIdx.x & 63;
    if (wid >= n) return;
    int base = __builtin_amdgcn_readfirstlane(off[wid]);
    int dg   = __builtin_amdgcn_readfirstlane(deg[wid]);
    float ax = 0.f, ay = 0.f;
    int j = 0;
    for (; j + 2 <= dg; j += 2) {
        int s0 = csr_src[base + j], s1 = csr_src[base + j + 1];
        float w0 = csr_w[base + j], w1 = csr_w[base + j + 1];
        unsigned u0 = *(const unsigned*)&xb[(long)s0 * DIM + lane * 2];
        unsigned u1 = *(const unsigned*)&xb[(long)s1 * DIM + lane * 2];
        ax = fmaf(w0, bflo(u0), ax); ay = fmaf(w0, bfhi(u0), ay);
        ax = fmaf(w1, bflo(u1), ax); ay = fmaf(w1, bfhi(u1), ay);
    }
    if (j < dg) {
        int s0 = csr_src[base + j];
        float w0 = csr_w[base + j];
        unsigned u0 = *(const unsigned*)&xb[(long)s0 * DIM + lane * 2];
        ax = fmaf(w0, bflo(u0), ax); ay = fmaf(w0, bfhi(u0), ay);
    }
    unsigned self = *(const unsigned*)&xb[(long)wid * DIM + lane * 2];
    unsigned res = snmask[wid] ? pack2(ax, ay) : self;
    *(unsigned*)&X[(long)wid * DIM + lane * 2] = res;
}

__global__ __launch_bounds__(256) void gatherL(const unsigned short* __restrict__ X,
                                               const int* __restrict__ off, const int* __restrict__ deg,
                                               const int* __restrict__ csr_src,
                                               unsigned short* __restrict__ H, int n) {
    int wid  = (blockIdx.x * blockDim.x + threadIdx.x) >> 6;
    int lane = threadIdx.x & 63;
    if (wid >= n) return;
    int base = __builtin_amdgcn_readfirstlane(off[wid]);
    int dg   = __builtin_amdgcn_readfirstlane(deg[wid]);
    unsigned self = *(const unsigned*)&X[(long)wid * DIM + lane * 2];
    float ax = bflo(self), ay = bfhi(self);   // GIN eps=0 self term
    int j = 0;
    for (; j + 2 <= dg; j += 2) {
        int s0 = csr_src[base + j], s1 = csr_src[base + j + 1];
        unsigned u0 = *(const unsigned*)&X[(long)s0 * DIM + lane * 2];
        unsigned u1 = *(const unsigned*)&X[(long)s1 * DIM + lane * 2];
        ax += bflo(u0); ay += bfhi(u0);
        ax += bflo(u1); ay += bfhi(u1);
    }
    if (j < dg) {
        int s0 = csr_src[base + j];
        unsigned u0 = *(const unsigned*)&X[(long)s0 * DIM + lane * 2];
        ax += bflo(u0); ay += bfhi(u0);
    }
    *(unsigned*)&H[(long)wid * DIM + lane * 2] = pack2(ax, ay);
}

// ---------------- MFMA MLP: H(bf16) -> Lin1+BN+ReLU -> Lin2+ReLU -> X(bf16) ----------------
// 512 threads = 8 waves. Block: 64 rows x 128 cols. Wave (wr=wid>>2, wc=wid&3): rows wr*32..+31, cols wc*32..+31.
// mfma_f32_16x16x32_bf16 layouts (gfx950, AMD lab-notes + m89-verified):
//   A: lane l elem j -> A[row = l&15][k = (l>>4)*8 + j]
//   B: lane l elem j -> B[k = (l>>4)*8 + j][col = l&15]   (loaded from WT[n][k], 16B contiguous)
//   D: lane l reg  v -> D[row = (l>>4)*4 + v][col = l&15]
#define HPITCH 136   // bf16 elems; 272B rows: 16B-aligned, 2-way LDS aliasing only

__global__ __launch_bounds__(512) void mlp_mfma(const unsigned short* __restrict__ H,
                                                unsigned short* __restrict__ X,
                                                const unsigned short* __restrict__ W1T,
                                                const unsigned short* __restrict__ W2T,
                                                const float* __restrict__ colA, const float* __restrict__ colB,
                                                const float* __restrict__ b2, int n) {
    __shared__ unsigned short h_t[64 * HPITCH];
    int t    = threadIdx.x;
    int wid  = t >> 6;
    int lane = t & 63;
    int wr   = wid >> 2;          // 0..1
    int wc   = wid & 3;           // 0..3
    int c0   = wc * 32;
    int lm   = lane & 15;
    int lk   = (lane >> 4) * 8;
    int row0 = blockIdx.x * 64 + wr * 32;

    // ---- A fragments from global H (rows clamped for tail block) ----
    bf16x8 a[2][4];
#pragma unroll
    for (int rs = 0; rs < 2; ++rs)
#pragma unroll
        for (int ks = 0; ks < 4; ++ks) {
            int r = row0 + rs * 16 + lm;
            if (r >= n) r = n - 1;
            a[rs][ks] = *(const bf16x8*)&H[(long)r * DIM + ks * 32 + lk];
        }

    // ---- B fragments for W1 ----
    bf16x8 b1[2][4];
#pragma unroll
    for (int cs = 0; cs < 2; ++cs)
#pragma unroll
        for (int ks = 0; ks < 4; ++ks) {
            int col = c0 + cs * 16 + lm;
            b1[cs][ks] = *(const bf16x8*)&W1T[col * DIM + ks * 32 + lk];
        }

    f32x4 acc[2][2];
    f32x4 z = {0.f, 0.f, 0.f, 0.f};
#pragma unroll
    for (int rs = 0; rs < 2; ++rs)
#pragma unroll
        for (int cs = 0; cs < 2; ++cs) acc[rs][cs] = z;

#pragma unroll
    for (int ks = 0; ks < 4; ++ks)
#pragma unroll
        for (int rs = 0; rs < 2; ++rs)
#pragma unroll
            for (int cs = 0; cs < 2; ++cs)
                acc[rs][cs] = __builtin_amdgcn_mfma_f32_16x16x32_bf16(a[rs][ks], b1[cs][ks], acc[rs][cs], 0, 0, 0);

    // ---- epilogue 1: affine(BN)+ReLU -> bf16 -> LDS ----
#pragma unroll
    for (int rs = 0; rs < 2; ++rs)
#pragma unroll
        for (int cs = 0; cs < 2; ++cs) {
            int colv = c0 + cs * 16 + lm;
            float cA = colA[colv], cB = colB[colv];
            int rbase = wr * 32 + rs * 16 + (lane >> 4) * 4;
            f32x4 av = acc[rs][cs];
#pragma unroll
            for (int v = 0; v < 4; ++v) {
                float h = fmaxf(fmaf(av[v], cA, cB), 0.f);
                h_t[(rbase + v) * HPITCH + colv] = f2b(h);
            }
        }
    __syncthreads();

    // ---- A2 fragments from LDS, B2 fragments from global ----
    bf16x8 a2[2][4];
#pragma unroll
    for (int rs = 0; rs < 2; ++rs)
#pragma unroll
        for (int ks = 0; ks < 4; ++ks)
            a2[rs][ks] = *(const bf16x8*)&h_t[(wr * 32 + rs * 16 + lm) * HPITCH + ks * 32 + lk];

    bf16x8 b2f[2][4];
#pragma unroll
    for (int cs = 0; cs < 2; ++cs)
#pragma unroll
        for (int ks = 0; ks < 4; ++ks) {
            int col = c0 + cs * 16 + lm;
            b2f[cs][ks] = *(const bf16x8*)&W2T[col * DIM + ks * 32 + lk];
        }

#pragma unroll
    for (int rs = 0; rs < 2; ++rs)
#pragma unroll
        for (int cs = 0; cs < 2; ++cs) acc[rs][cs] = z;

#pragma unroll
    for (int ks = 0; ks < 4; ++ks)
#pragma unroll
        for (int rs = 0; rs < 2; ++rs)
#pragma unroll
            for (int cs = 0; cs < 2; ++cs)
                acc[rs][cs] = __builtin_amdgcn_mfma_f32_16x16x32_bf16(a2[rs][ks], b2f[cs][ks], acc[rs][cs], 0, 0, 0);

    __syncthreads();   // all h_t reads done before overwrite

    // ---- epilogue 2: +bias, ReLU -> bf16 -> LDS ----
#pragma unroll
    for (int rs = 0; rs < 2; ++rs)
#pragma unroll
        for (int cs = 0; cs < 2; ++cs) {
            int colv = c0 + cs * 16 + lm;
            float bb = b2[colv];
            int rbase = wr * 32 + rs * 16 + (lane >> 4) * 4;
            f32x4 av = acc[rs][cs];
#pragma unroll
            for (int v = 0; v < 4; ++v) {
                float h = fmaxf(av[v] + bb, 0.f);
                h_t[(rbase + v) * HPITCH + colv] = f2b(h);
            }
        }
    __syncthreads();

    // ---- coalesced copy-out: 64 rows, 8 threads/row, 16 elems (32B) per thread ----
    {
        int row = t >> 3;
        int ch  = (t & 7) * 16;
        int gr  = blockIdx.x * 64 + row;
        if (gr < n) {
            *(bf16x8*)&X[(long)gr * DIM + ch]     = *(const bf16x8*)&h_t[row * HPITCH + ch];
            *(bf16x8*)&X[(long)gr * DIM + ch + 8] = *(const bf16x8*)&h_t[row * HPITCH + ch + 8];
        }
    }
}

// ---------------- pool (batch sorted -> run-accumulate) ----------------

__global__ __launch_bounds__(128) void pool_kernel(const unsigned short* __restrict__ X,
                                                   const int* __restrict__ batch,
                                                   float* __restrict__ POOL, int n) {
    int c  = threadIdx.x;
    int n0 = blockIdx.x * 128;
    if (n0 >= n) return;
    int n1 = n0 + 128; if (n1 > n) n1 = n;
    int gcur = batch[n0];
    float acc = 0.f;
    for (int i = n0; i < n1; ++i) {
        int g = batch[i];
        if (g != gcur) {
            atomicAdd(&POOL[(long)gcur * DIM + c], acc);
            acc = 0.f; gcur = g;
        }
        acc += __uint_as_float(((unsigned)X[(long)i * DIM + c]) << 16);
    }
    atomicAdd(&POOL[(long)gcur * DIM + c], acc);
}

// ---------------- final head ----------------

__global__ __launch_bounds__(128) void final_mlp(const float* __restrict__ POOL,
                                                 const float* __restrict__ Wf1, const float* __restrict__ bf1,
                                                 const float* __restrict__ Wf2, const float* __restrict__ bf2,
                                                 float* __restrict__ out) {
    int g = blockIdx.x;
    int t = threadIdx.x;
    __shared__ float p[128];
    __shared__ float h[128];
    p[t] = POOL[(long)g * DIM + t];
    __syncthreads();
    float acc = bf1[t];
#pragma unroll 8
    for (int k = 0; k < DIM; ++k) acc = fmaf(p[k], Wf1[k * DIM + t], acc);
    h[t] = fmaxf(acc, 0.f);
    __syncthreads();
    if (t < NCLS) {
        float acc2 = bf2[t];
#pragma unroll 8
        for (int k = 0; k < DIM; ++k) acc2 = fmaf(h[k], Wf2[k * NCLS + t], acc2);
        out[(long)g * NCLS + t] = acc2;
    }
}

// ---------------- launch ----------------

extern "C" void kernel_launch(void* const* d_in, const int* in_sizes, int n_in,
                              void* d_out, int out_size, void* d_ws, size_t ws_size,
                              hipStream_t stream) {
    const float* x      = (const float*)d_in[0];
    const int*   ei     = (const int*)d_in[1];
    const int*   snmask = (const int*)d_in[2];
    const float* emask  = (const float*)d_in[3];
    const int*   batch  = (const int*)d_in[4];
    const float* Ws1    = (const float*)d_in[5];
    const float* bs1    = (const float*)d_in[6];
    const float* gamma  = (const float*)d_in[7];
    const float* beta   = (const float*)d_in[8];
    const float* mean   = (const float*)d_in[9];
    const float* var    = (const float*)d_in[10];
    const float* Ws2    = (const float*)d_in[11];
    const float* bs2    = (const float*)d_in[12];
    const float* Wf1    = (const float*)d_in[13];
    const float* bf1    = (const float*)d_in[14];
    const float* Wf2    = (const float*)d_in[15];
    const float* bf2    = (const float*)d_in[16];
    float* out = (float*)d_out;

    const int* srcp = ei;
    const int* dstp = ei + NEDGES;

    char* ws = (char*)d_ws;
    size_t o = 0;
    auto alloc = [&](size_t bytes) -> void* {
        void* p = ws + o;
        o = (o + bytes + 255) & ~(size_t)255;
        return p;
    };
    unsigned short* XB  = (unsigned short*)alloc((size_t)NNODES * DIM * 2);
    unsigned short* X   = (unsigned short*)alloc((size_t)NNODES * DIM * 2);
    unsigned short* H   = (unsigned short*)alloc((size_t)NNODES * DIM * 2);
    int*   deg     = (int*)alloc((size_t)NNODES * 4);
    int*   off     = (int*)alloc((size_t)NNODES * 4);
    int*   cursor  = (int*)alloc((size_t)NNODES * 4);
    int*   csr_src = (int*)alloc((size_t)NEDGES * 4);
    float* csr_w   = (float*)alloc((size_t)NEDGES * 4);
    float* colA    = (float*)alloc((size_t)NLAYERS * DIM * 4);
    float* colB    = (float*)alloc((size_t)NLAYERS * DIM * 4);
    unsigned short* W1T = (unsigned short*)alloc((size_t)NLAYERS * DIM * DIM * 2);
    unsigned short* W2T = (unsigned short*)alloc((size_t)NLAYERS * DIM * DIM * 2);
    float* POOL    = (float*)alloc((size_t)NGRAPH * DIM * 4);

    (void)hipMemsetAsync(deg, 0, (size_t)NNODES * 4, stream);
    (void)hipMemsetAsync(POOL, 0, (size_t)NGRAPH * DIM * 4, stream);

    count_deg<<<(NEDGES + 255) / 256, 256, 0, stream>>>(dstp, deg, NEDGES);
    scan_deg<<<1, 1024, 0, stream>>>(deg, off, cursor, NNODES);
    fill_csr<<<(NEDGES + 255) / 256, 256, 0, stream>>>(srcp, dstp, emask, cursor, csr_src, csr_w, NEDGES);
    prep_bn<<<(NLAYERS * DIM + 255) / 256, 256, 0, stream>>>(gamma, beta, mean, var, bs1, colA, colB, NLAYERS * DIM);
    prep_wt<<<(NLAYERS * DIM * DIM + 255) / 256, 256, 0, stream>>>(Ws1, Ws2, W1T, W2T, NLAYERS * DIM * DIM);
    conv_x<<<(NNODES * DIM / 4 + 255) / 256, 256, 0, stream>>>(x, XB, NNODES * DIM / 4);

    const int gatherBlocks = (NNODES * 64 + 255) / 256;  // wave per node
    gather0<<<gatherBlocks, 256, 0, stream>>>(XB, off, deg, csr_src, csr_w, snmask, X, NNODES);

    const int mlpBlocks = (NNODES + 63) / 64;
    for (int l = 0; l < NLAYERS; ++l) {
        gatherL<<<gatherBlocks, 256, 0, stream>>>(X, off, deg, csr_src, H, NNODES);
        mlp_mfma<<<mlpBlocks, 512, 0, stream>>>(H, X,
                                                W1T + (size_t)l * DIM * DIM,
                                                W2T + (size_t)l * DIM * DIM,
                                                colA + (size_t)l * DIM,
                                                colB + (size_t)l * DIM,
                                                bs2 + (size_t)l * DIM, NNODES);
    }

    pool_kernel<<<(NNODES + 127) / 128, 128, 0, stream>>>(X, batch, POOL, NNODES);
    final_mlp<<<NGRAPH, 128, 0, stream>>>(POOL, Wf1, bf1, Wf2, bf2, out);
}

// Round 5
// 331.889 us; speedup vs baseline: 2.5184x; 1.3611x over previous
//
#include <hip/hip_runtime.h>
#include <hip/hip_bf16.h>

#define NNODES 50000
#define NEDGES 600000
#define DIM    128
#define NLAYERS 3
#define NCLS   10
#define NGRAPH 256
#define BN_EPS 1e-5f

#define SCAN_BLK 256
#define NSB ((NNODES + SCAN_BLK - 1) / SCAN_BLK)   // 196 blocks

typedef __attribute__((ext_vector_type(8))) short bf16x8;   // 8 bf16 = 4 VGPR
typedef __attribute__((ext_vector_type(4))) float f32x4;

static __device__ __forceinline__ unsigned short f2b(float f) {
    union { __hip_bfloat16 h; unsigned short u; } c;
    c.h = __float2bfloat16(f);
    return c.u;
}
static __device__ __forceinline__ float bflo(unsigned u) { return __uint_as_float(u << 16); }
static __device__ __forceinline__ float bfhi(unsigned u) { return __uint_as_float(u & 0xffff0000u); }
static __device__ __forceinline__ unsigned pack2(float a, float b) {
    return (unsigned)f2b(a) | ((unsigned)f2b(b) << 16);
}

// ---------------- CSR build ----------------

__global__ void count_deg(const int* __restrict__ dst, int* __restrict__ deg, int E) {
    int e = blockIdx.x * blockDim.x + threadIdx.x;
    if (e < E) atomicAdd(&deg[dst[e]], 1);
}

// 3-phase device-wide exclusive scan of deg -> off/cursor.
// Phase 1: per-block sums (196 blocks, shuffle-reduce).
__global__ __launch_bounds__(SCAN_BLK) void partial_sum(const int* __restrict__ deg,
                                                        int* __restrict__ part, int n) {
    int t = threadIdx.x;
    int i = blockIdx.x * SCAN_BLK + t;
    int v = (i < n) ? deg[i] : 0;
#pragma unroll
    for (int o = 32; o > 0; o >>= 1) v += __shfl_down(v, o, 64);
    __shared__ int s[SCAN_BLK / 64];
    if ((t & 63) == 0) s[t >> 6] = v;
    __syncthreads();
    if (t == 0) {
        int sum = 0;
#pragma unroll
        for (int w = 0; w < SCAN_BLK / 64; ++w) sum += s[w];
        part[blockIdx.x] = sum;
    }
}

// Phase 2: one block scans the partials into exclusive block bases.
__global__ __launch_bounds__(256) void scan_partials(int* __restrict__ part, int nb) {
    __shared__ int s[256];
    int t = threadIdx.x;
    int v = (t < nb) ? part[t] : 0;
    s[t] = v;
    __syncthreads();
    for (int o = 1; o < 256; o <<= 1) {
        int u = (t >= o) ? s[t - o] : 0;
        __syncthreads();
        s[t] += u;
        __syncthreads();
    }
    if (t < nb) part[t] = (t == 0) ? 0 : s[t - 1];
}

// Phase 3: intra-block exclusive scan + block base -> off, cursor.
__global__ __launch_bounds__(SCAN_BLK) void emit_offsets(const int* __restrict__ deg,
                                                         const int* __restrict__ part,
                                                         int* __restrict__ off,
                                                         int* __restrict__ cursor, int n) {
    __shared__ int s[SCAN_BLK];
    int t = threadIdx.x;
    int i = blockIdx.x * SCAN_BLK + t;
    int v = (i < n) ? deg[i] : 0;
    s[t] = v;
    __syncthreads();
    for (int o = 1; o < SCAN_BLK; o <<= 1) {
        int u = (t >= o) ? s[t - o] : 0;
        __syncthreads();
        s[t] += u;
        __syncthreads();
    }
    if (i < n) {
        int excl = part[blockIdx.x] + s[t] - v;
        off[i] = excl;
        cursor[i] = excl;
    }
}

__global__ void fill_csr(const int* __restrict__ src, const int* __restrict__ dst,
                         const float* __restrict__ emask,
                         int* __restrict__ cursor,
                         int* __restrict__ csr_src, float* __restrict__ csr_w, int E) {
    int e = blockIdx.x * blockDim.x + threadIdx.x;
    if (e < E) {
        int d = dst[e];
        int p = atomicAdd(&cursor[d], 1);
        csr_src[p] = src[e];
        csr_w[p]   = emask[e];
    }
}

// ---------------- prep: BN fold, W transpose->bf16, x->bf16 ----------------

__global__ void prep_bn(const float* __restrict__ gamma, const float* __restrict__ beta,
                        const float* __restrict__ mean, const float* __restrict__ var,
                        const float* __restrict__ b1,
                        float* __restrict__ colA, float* __restrict__ colB, int n) {
    int i = blockIdx.x * blockDim.x + threadIdx.x;
    if (i < n) {
        float A = gamma[i] * rsqrtf(var[i] + BN_EPS);
        colA[i] = A;
        colB[i] = beta[i] - mean[i] * A + b1[i] * A;
    }
}

// W[l][k][n] f32  ->  WT[l][n][k] bf16
__global__ void prep_wt(const float* __restrict__ W1, const float* __restrict__ W2,
                        unsigned short* __restrict__ W1T, unsigned short* __restrict__ W2T, int total) {
    int i = blockIdx.x * blockDim.x + threadIdx.x;
    if (i < total) {
        int l  = i / (DIM * DIM);
        int r  = i - l * DIM * DIM;
        int nn = r / DIM;
        int kk = r - nn * DIM;
        int sidx = l * DIM * DIM + kk * DIM + nn;
        W1T[i] = f2b(W1[sidx]);
        W2T[i] = f2b(W2[sidx]);
    }
}

__global__ void conv_x(const float* __restrict__ x, unsigned short* __restrict__ xb, int n4) {
    int i = blockIdx.x * blockDim.x + threadIdx.x;
    if (i < n4) {
        float4 v = ((const float4*)x)[i];
        unsigned lo = pack2(v.x, v.y);
        unsigned hi = pack2(v.z, v.w);
        ((uint2*)xb)[i] = make_uint2(lo, hi);
    }
}

// ---------------- gathers (wave per node, u32=2bf16 per lane, 4x unrolled) ----------------

__global__ __launch_bounds__(256) void gather0(const unsigned short* __restrict__ xb,
                                               const int* __restrict__ off, const int* __restrict__ deg,
                                               const int* __restrict__ csr_src, const float* __restrict__ csr_w,
                                               const int* __restrict__ snmask,
                                               unsigned short* __restrict__ X, int n) {
    int wid  = (blockIdx.x * blockDim.x + threadIdx.x) >> 6;
    int lane = threadIdx.x & 63;
    if (wid >= n) return;
    int base = __builtin_amdgcn_readfirstlane(off[wid]);
    int dg   = __builtin_amdgcn_readfirstlane(deg[wid]);
    float ax = 0.f, ay = 0.f;
    int j = 0;
    for (; j + 4 <= dg; j += 4) {
        int s0 = csr_src[base + j],     s1 = csr_src[base + j + 1];
        int s2 = csr_src[base + j + 2], s3 = csr_src[base + j + 3];
        float w0 = csr_w[base + j],     w1 = csr_w[base + j + 1];
        float w2 = csr_w[base + j + 2], w3 = csr_w[base + j + 3];
        unsigned u0 = *(const unsigned*)&xb[(long)s0 * DIM + lane * 2];
        unsigned u1 = *(const unsigned*)&xb[(long)s1 * DIM + lane * 2];
        unsigned u2 = *(const unsigned*)&xb[(long)s2 * DIM + lane * 2];
        unsigned u3 = *(const unsigned*)&xb[(long)s3 * DIM + lane * 2];
        ax = fmaf(w0, bflo(u0), ax); ay = fmaf(w0, bfhi(u0), ay);
        ax = fmaf(w1, bflo(u1), ax); ay = fmaf(w1, bfhi(u1), ay);
        ax = fmaf(w2, bflo(u2), ax); ay = fmaf(w2, bfhi(u2), ay);
        ax = fmaf(w3, bflo(u3), ax); ay = fmaf(w3, bfhi(u3), ay);
    }
    for (; j < dg; ++j) {
        int s0 = csr_src[base + j];
        float w0 = csr_w[base + j];
        unsigned u0 = *(const unsigned*)&xb[(long)s0 * DIM + lane * 2];
        ax = fmaf(w0, bflo(u0), ax); ay = fmaf(w0, bfhi(u0), ay);
    }
    unsigned self = *(const unsigned*)&xb[(long)wid * DIM + lane * 2];
    unsigned res = snmask[wid] ? pack2(ax, ay) : self;
    *(unsigned*)&X[(long)wid * DIM + lane * 2] = res;
}

__global__ __launch_bounds__(256) void gatherL(const unsigned short* __restrict__ X,
                                               const int* __restrict__ off, const int* __restrict__ deg,
                                               const int* __restrict__ csr_src,
                                               unsigned short* __restrict__ H, int n) {
    int wid  = (blockIdx.x * blockDim.x + threadIdx.x) >> 6;
    int lane = threadIdx.x & 63;
    if (wid >= n) return;
    int base = __builtin_amdgcn_readfirstlane(off[wid]);
    int dg   = __builtin_amdgcn_readfirstlane(deg[wid]);
    unsigned self = *(const unsigned*)&X[(long)wid * DIM + lane * 2];
    float ax = bflo(self), ay = bfhi(self);   // GIN eps=0 self term
    int j = 0;
    for (; j + 4 <= dg; j += 4) {
        int s0 = csr_src[base + j],     s1 = csr_src[base + j + 1];
        int s2 = csr_src[base + j + 2], s3 = csr_src[base + j + 3];
        unsigned u0 = *(const unsigned*)&X[(long)s0 * DIM + lane * 2];
        unsigned u1 = *(const unsigned*)&X[(long)s1 * DIM + lane * 2];
        unsigned u2 = *(const unsigned*)&X[(long)s2 * DIM + lane * 2];
        unsigned u3 = *(const unsigned*)&X[(long)s3 * DIM + lane * 2];
        ax += bflo(u0); ay += bfhi(u0);
        ax += bflo(u1); ay += bfhi(u1);
        ax += bflo(u2); ay += bfhi(u2);
        ax += bflo(u3); ay += bfhi(u3);
    }
    for (; j < dg; ++j) {
        int s0 = csr_src[base + j];
        unsigned u0 = *(const unsigned*)&X[(long)s0 * DIM + lane * 2];
        ax += bflo(u0); ay += bfhi(u0);
    }
    *(unsigned*)&H[(long)wid * DIM + lane * 2] = pack2(ax, ay);
}

// ---------------- MFMA MLP: H(bf16) -> Lin1+BN+ReLU -> Lin2+ReLU -> X(bf16) ----------------
// 512 threads = 8 waves. Block: 64 rows x 128 cols. Wave (wr=wid>>2, wc=wid&3): rows wr*32..+31, cols wc*32..+31.
// mfma_f32_16x16x32_bf16 layouts (gfx950, m89-verified):
//   A: lane l elem j -> A[row = l&15][k = (l>>4)*8 + j]
//   B: lane l elem j -> B[k = (l>>4)*8 + j][col = l&15]   (loaded from WT[n][k], 16B contiguous)
//   D: lane l reg  v -> D[row = (l>>4)*4 + v][col = l&15]
#define HPITCH 136   // bf16 elems; 272B rows: 16B-aligned, 2-way LDS aliasing only

__global__ __launch_bounds__(512) void mlp_mfma(const unsigned short* __restrict__ H,
                                                unsigned short* __restrict__ X,
                                                const unsigned short* __restrict__ W1T,
                                                const unsigned short* __restrict__ W2T,
                                                const float* __restrict__ colA, const float* __restrict__ colB,
                                                const float* __restrict__ b2, int n) {
    __shared__ unsigned short h_t[64 * HPITCH];
    int t    = threadIdx.x;
    int wid  = t >> 6;
    int lane = t & 63;
    int wr   = wid >> 2;          // 0..1
    int wc   = wid & 3;           // 0..3
    int c0   = wc * 32;
    int lm   = lane & 15;
    int lk   = (lane >> 4) * 8;
    int row0 = blockIdx.x * 64 + wr * 32;

    // ---- A fragments from global H (rows clamped for tail block) ----
    bf16x8 a[2][4];
#pragma unroll
    for (int rs = 0; rs < 2; ++rs)
#pragma unroll
        for (int ks = 0; ks < 4; ++ks) {
            int r = row0 + rs * 16 + lm;
            if (r >= n) r = n - 1;
            a[rs][ks] = *(const bf16x8*)&H[(long)r * DIM + ks * 32 + lk];
        }

    // ---- B fragments for W1 ----
    bf16x8 b1[2][4];
#pragma unroll
    for (int cs = 0; cs < 2; ++cs)
#pragma unroll
        for (int ks = 0; ks < 4; ++ks) {
            int col = c0 + cs * 16 + lm;
            b1[cs][ks] = *(const bf16x8*)&W1T[col * DIM + ks * 32 + lk];
        }

    f32x4 acc[2][2];
    f32x4 z = {0.f, 0.f, 0.f, 0.f};
#pragma unroll
    for (int rs = 0; rs < 2; ++rs)
#pragma unroll
        for (int cs = 0; cs < 2; ++cs) acc[rs][cs] = z;

#pragma unroll
    for (int ks = 0; ks < 4; ++ks)
#pragma unroll
        for (int rs = 0; rs < 2; ++rs)
#pragma unroll
            for (int cs = 0; cs < 2; ++cs)
                acc[rs][cs] = __builtin_amdgcn_mfma_f32_16x16x32_bf16(a[rs][ks], b1[cs][ks], acc[rs][cs], 0, 0, 0);

    // ---- epilogue 1: affine(BN)+ReLU -> bf16 -> LDS ----
#pragma unroll
    for (int rs = 0; rs < 2; ++rs)
#pragma unroll
        for (int cs = 0; cs < 2; ++cs) {
            int colv = c0 + cs * 16 + lm;
            float cA = colA[colv], cB = colB[colv];
            int rbase = wr * 32 + rs * 16 + (lane >> 4) * 4;
            f32x4 av = acc[rs][cs];
#pragma unroll
            for (int v = 0; v < 4; ++v) {
                float h = fmaxf(fmaf(av[v], cA, cB), 0.f);
                h_t[(rbase + v) * HPITCH + colv] = f2b(h);
            }
        }
    __syncthreads();

    // ---- A2 fragments from LDS, B2 fragments from global ----
    bf16x8 a2[2][4];
#pragma unroll
    for (int rs = 0; rs < 2; ++rs)
#pragma unroll
        for (int ks = 0; ks < 4; ++ks)
            a2[rs][ks] = *(const bf16x8*)&h_t[(wr * 32 + rs * 16 + lm) * HPITCH + ks * 32 + lk];

    bf16x8 b2f[2][4];
#pragma unroll
    for (int cs = 0; cs < 2; ++cs)
#pragma unroll
        for (int ks = 0; ks < 4; ++ks) {
            int col = c0 + cs * 16 + lm;
            b2f[cs][ks] = *(const bf16x8*)&W2T[col * DIM + ks * 32 + lk];
        }

#pragma unroll
    for (int rs = 0; rs < 2; ++rs)
#pragma unroll
        for (int cs = 0; cs < 2; ++cs) acc[rs][cs] = z;

#pragma unroll
    for (int ks = 0; ks < 4; ++ks)
#pragma unroll
        for (int rs = 0; rs < 2; ++rs)
#pragma unroll
            for (int cs = 0; cs < 2; ++cs)
                acc[rs][cs] = __builtin_amdgcn_mfma_f32_16x16x32_bf16(a2[rs][ks], b2f[cs][ks], acc[rs][cs], 0, 0, 0);

    __syncthreads();   // all h_t reads done before overwrite

    // ---- epilogue 2: +bias, ReLU -> bf16 -> LDS ----
#pragma unroll
    for (int rs = 0; rs < 2; ++rs)
#pragma unroll
        for (int cs = 0; cs < 2; ++cs) {
            int colv = c0 + cs * 16 + lm;
            float bb = b2[colv];
            int rbase = wr * 32 + rs * 16 + (lane >> 4) * 4;
            f32x4 av = acc[rs][cs];
#pragma unroll
            for (int v = 0; v < 4; ++v) {
                float h = fmaxf(av[v] + bb, 0.f);
                h_t[(rbase + v) * HPITCH + colv] = f2b(h);
            }
        }
    __syncthreads();

    // ---- coalesced copy-out: 64 rows, 8 threads/row, 16 elems (32B) per thread ----
    {
        int row = t >> 3;
        int ch  = (t & 7) * 16;
        int gr  = blockIdx.x * 64 + row;
        if (gr < n) {
            *(bf16x8*)&X[(long)gr * DIM + ch]     = *(const bf16x8*)&h_t[row * HPITCH + ch];
            *(bf16x8*)&X[(long)gr * DIM + ch + 8] = *(const bf16x8*)&h_t[row * HPITCH + ch + 8];
        }
    }
}

// ---------------- pool (batch sorted -> run-accumulate) ----------------

__global__ __launch_bounds__(128) void pool_kernel(const unsigned short* __restrict__ X,
                                                   const int* __restrict__ batch,
                                                   float* __restrict__ POOL, int n) {
    int c  = threadIdx.x;
    int n0 = blockIdx.x * 128;
    if (n0 >= n) return;
    int n1 = n0 + 128; if (n1 > n) n1 = n;
    int gcur = batch[n0];
    float acc = 0.f;
    for (int i = n0; i < n1; ++i) {
        int g = batch[i];
        if (g != gcur) {
            atomicAdd(&POOL[(long)gcur * DIM + c], acc);
            acc = 0.f; gcur = g;
        }
        acc += __uint_as_float(((unsigned)X[(long)i * DIM + c]) << 16);
    }
    atomicAdd(&POOL[(long)gcur * DIM + c], acc);
}

// ---------------- final head ----------------

__global__ __launch_bounds__(128) void final_mlp(const float* __restrict__ POOL,
                                                 const float* __restrict__ Wf1, const float* __restrict__ bf1,
                                                 const float* __restrict__ Wf2, const float* __restrict__ bf2,
                                                 float* __restrict__ out) {
    int g = blockIdx.x;
    int t = threadIdx.x;
    __shared__ float p[128];
    __shared__ float h[128];
    p[t] = POOL[(long)g * DIM + t];
    __syncthreads();
    float acc = bf1[t];
#pragma unroll 8
    for (int k = 0; k < DIM; ++k) acc = fmaf(p[k], Wf1[k * DIM + t], acc);
    h[t] = fmaxf(acc, 0.f);
    __syncthreads();
    if (t < NCLS) {
        float acc2 = bf2[t];
#pragma unroll 8
        for (int k = 0; k < DIM; ++k) acc2 = fmaf(h[k], Wf2[k * NCLS + t], acc2);
        out[(long)g * NCLS + t] = acc2;
    }
}

// ---------------- launch ----------------

extern "C" void kernel_launch(void* const* d_in, const int* in_sizes, int n_in,
                              void* d_out, int out_size, void* d_ws, size_t ws_size,
                              hipStream_t stream) {
    const float* x      = (const float*)d_in[0];
    const int*   ei     = (const int*)d_in[1];
    const int*   snmask = (const int*)d_in[2];
    const float* emask  = (const float*)d_in[3];
    const int*   batch  = (const int*)d_in[4];
    const float* Ws1    = (const float*)d_in[5];
    const float* bs1    = (const float*)d_in[6];
    const float* gamma  = (const float*)d_in[7];
    const float* beta   = (const float*)d_in[8];
    const float* mean   = (const float*)d_in[9];
    const float* var    = (const float*)d_in[10];
    const float* Ws2    = (const float*)d_in[11];
    const float* bs2    = (const float*)d_in[12];
    const float* Wf1    = (const float*)d_in[13];
    const float* bf1    = (const float*)d_in[14];
    const float* Wf2    = (const float*)d_in[15];
    const float* bf2    = (const float*)d_in[16];
    float* out = (float*)d_out;

    const int* srcp = ei;
    const int* dstp = ei + NEDGES;

    char* ws = (char*)d_ws;
    size_t o = 0;
    auto alloc = [&](size_t bytes) -> void* {
        void* p = ws + o;
        o = (o + bytes + 255) & ~(size_t)255;
        return p;
    };
    unsigned short* XB  = (unsigned short*)alloc((size_t)NNODES * DIM * 2);
    unsigned short* X   = (unsigned short*)alloc((size_t)NNODES * DIM * 2);
    unsigned short* H   = (unsigned short*)alloc((size_t)NNODES * DIM * 2);
    int*   deg     = (int*)alloc((size_t)NNODES * 4);
    int*   off     = (int*)alloc((size_t)NNODES * 4);
    int*   cursor  = (int*)alloc((size_t)NNODES * 4);
    int*   part    = (int*)alloc((size_t)NSB * 4);
    int*   csr_src = (int*)alloc((size_t)NEDGES * 4);
    float* csr_w   = (float*)alloc((size_t)NEDGES * 4);
    float* colA    = (float*)alloc((size_t)NLAYERS * DIM * 4);
    float* colB    = (float*)alloc((size_t)NLAYERS * DIM * 4);
    unsigned short* W1T = (unsigned short*)alloc((size_t)NLAYERS * DIM * DIM * 2);
    unsigned short* W2T = (unsigned short*)alloc((size_t)NLAYERS * DIM * DIM * 2);
    float* POOL    = (float*)alloc((size_t)NGRAPH * DIM * 4);

    (void)hipMemsetAsync(deg, 0, (size_t)NNODES * 4, stream);
    (void)hipMemsetAsync(POOL, 0, (size_t)NGRAPH * DIM * 4, stream);

    count_deg<<<(NEDGES + 255) / 256, 256, 0, stream>>>(dstp, deg, NEDGES);
    partial_sum<<<NSB, SCAN_BLK, 0, stream>>>(deg, part, NNODES);
    scan_partials<<<1, 256, 0, stream>>>(part, NSB);
    emit_offsets<<<NSB, SCAN_BLK, 0, stream>>>(deg, part, off, cursor, NNODES);
    fill_csr<<<(NEDGES + 255) / 256, 256, 0, stream>>>(srcp, dstp, emask, cursor, csr_src, csr_w, NEDGES);
    prep_bn<<<(NLAYERS * DIM + 255) / 256, 256, 0, stream>>>(gamma, beta, mean, var, bs1, colA, colB, NLAYERS * DIM);
    prep_wt<<<(NLAYERS * DIM * DIM + 255) / 256, 256, 0, stream>>>(Ws1, Ws2, W1T, W2T, NLAYERS * DIM * DIM);
    conv_x<<<(NNODES * DIM / 4 + 255) / 256, 256, 0, stream>>>(x, XB, NNODES * DIM / 4);

    const int gatherBlocks = (NNODES * 64 + 255) / 256;  // wave per node
    gather0<<<gatherBlocks, 256, 0, stream>>>(XB, off, deg, csr_src, csr_w, snmask, X, NNODES);

    const int mlpBlocks = (NNODES + 63) / 64;
    for (int l = 0; l < NLAYERS; ++l) {
        gatherL<<<gatherBlocks, 256, 0, stream>>>(X, off, deg, csr_src, H, NNODES);
        mlp_mfma<<<mlpBlocks, 512, 0, stream>>>(H, X,
                                                W1T + (size_t)l * DIM * DIM,
                                                W2T + (size_t)l * DIM * DIM,
                                                colA + (size_t)l * DIM,
                                                colB + (size_t)l * DIM,
                                                bs2 + (size_t)l * DIM, NNODES);
    }

    pool_kernel<<<(NNODES + 127) / 128, 128, 0, stream>>>(X, batch, POOL, NNODES);
    final_mlp<<<NGRAPH, 128, 0, stream>>>(POOL, Wf1, bf1, Wf2, bf2, out);
}